// Round 1
// baseline (322.618 us; speedup 1.0000x reference)
//
#include <hip/hip_runtime.h>
#include <math.h>
#include <stdint.h>

#define NF_    13776
#define R_     128
#define NPIX_  (R_ * R_)
#define NSLICE_ 16
#define FPS_   ((NF_ + NSLICE_ - 1) / NSLICE_)   // 861

// fdat layout: 15 arrays of NF_ floats (last is cull flag as int)
#define OFF_A    0
#define OFF_B    1
#define OFF_C    2
#define OFF_D    3
#define OFF_X2   4
#define OFF_Y2   5
#define OFF_DET  6
#define OFF_Z0   7
#define OFF_Z1   8
#define OFF_Z2   9
#define OFF_XMIN 10
#define OFF_XMAX 11
#define OFF_YMIN 12
#define OFF_YMAX 13
#define OFF_CULL 14

// exact f32 constants matching the JAX reference (computed from doubles)
#define EYEZ_F   (-2.7320508075688772935f)       // -(1/tan(30deg) + 1)
#define INV_FAR_F (0.04f)                        // f32(1.0/25.0)
#define INV_NEAR_F (10.0f)                       // f32(1.0/0.1)
#define FAR_BITS 0x41C80000u                     // bits of 25.0f
#define HIT_THR_F ((float)(25.0 * (1.0 - 1e-06)))

static __device__ __forceinline__ float pix_coord(int j) {
    // (2*j + 1 - 128)/128 : exact in f32 (odd integer / power of two)
    return (2.0f * (float)j + 1.0f - 128.0f) / 128.0f;
}

__global__ __launch_bounds__(256) void kpre(const float* __restrict__ verts,
                                            const int* __restrict__ faces,
                                            float* __restrict__ fdat)
{
#pragma clang fp contract(off)
    int f = blockIdx.x * 256 + threadIdx.x;
    if (f >= NF_) return;
    int i0 = faces[3*f+0], i1 = faces[3*f+1], i2 = faces[3*f+2];
    float x0 = verts[3*i0+0], y0 = verts[3*i0+1], z0 = verts[3*i0+2] - EYEZ_F;
    float x1 = verts[3*i1+0], y1 = verts[3*i1+1], z1 = verts[3*i1+2] - EYEZ_F;
    float x2 = verts[3*i2+0], y2 = verts[3*i2+1], z2 = verts[3*i2+2] - EYEZ_F;

    float a = y1 - y2;          // w0 coeff on (px - x2)
    float b = x2 - x1;          // w0 coeff on (py - y2)
    float c = y2 - y0;          // w1 coeff on (px - x2)
    float d = x0 - x2;          // w1 coeff on (py - y2)
    float e = y0 - y2;
    float det = a * d + b * e;  // (y1-y2)*(x0-x2) + (x2-x1)*(y0-y2), no FMA
    bool det_ok = fabsf(det) > 1e-10f;
    float dets = det_ok ? det : 1e-10f;
    bool zpos = (z0 > 0.1f) && (z1 > 0.1f) && (z2 > 0.1f);

    float xmin = fminf(x0, fminf(x1, x2)) - 1e-4f;
    float xmax = fmaxf(x0, fmaxf(x1, x2)) + 1e-4f;
    float ymin = fminf(y0, fminf(y1, y2)) - 1e-4f;
    float ymax = fmaxf(y0, fmaxf(y1, y2)) + 1e-4f;

    fdat[OFF_A*NF_ + f] = a;
    fdat[OFF_B*NF_ + f] = b;
    fdat[OFF_C*NF_ + f] = c;
    fdat[OFF_D*NF_ + f] = d;
    fdat[OFF_X2*NF_ + f] = x2;
    fdat[OFF_Y2*NF_ + f] = y2;
    fdat[OFF_DET*NF_ + f] = dets;
    fdat[OFF_Z0*NF_ + f] = z0;
    fdat[OFF_Z1*NF_ + f] = z1;
    fdat[OFF_Z2*NF_ + f] = z2;
    fdat[OFF_XMIN*NF_ + f] = xmin;
    fdat[OFF_XMAX*NF_ + f] = xmax;
    fdat[OFF_YMIN*NF_ + f] = ymin;
    fdat[OFF_YMAX*NF_ + f] = ymax;
    ((int*)fdat)[OFF_CULL*NF_ + f] = (det_ok && zpos) ? 0 : 1;
}

__global__ __launch_bounds__(256) void kinit(unsigned long long* __restrict__ pd64)
{
    int p = blockIdx.x * 256 + threadIdx.x;
    if (p < NPIX_) pd64[p] = ((unsigned long long)FAR_BITS << 32);  // depth=FAR, fid=0
}

__global__ __launch_bounds__(256) void kscan(const float* __restrict__ fdat,
                                             unsigned long long* __restrict__ pd64)
{
#pragma clang fp contract(off)
    __shared__ float la[256], lb[256], lc[256], ld[256];
    __shared__ float lx2[256], ly2[256], ldet[256];
    __shared__ float lz0[256], lz1[256], lz2[256];
    __shared__ int   lfid[256];
    __shared__ int   wcnt[4];

    const int tile  = blockIdx.x;      // 0..63 : 8x8 tiles of 16x16 px
    const int slice = blockIdx.y;      // 0..NSLICE_-1
    const int tr = tile >> 3, tc = tile & 7;
    const int tid = threadIdx.x;
    const int ti = tid >> 4, tj = tid & 15;
    const int ii = tr * 16 + ti, jj = tc * 16 + tj;

    const float px = pix_coord(jj);
    const float py = -pix_coord(ii);
    // tile bounds in NDC
    const float tpx0 = pix_coord(tc * 16);
    const float tpx1 = pix_coord(tc * 16 + 15);
    const float tpy0 = -pix_coord(tr * 16 + 15);
    const float tpy1 = -pix_coord(tr * 16);

    const int f0 = slice * FPS_;
    const int f1 = min(NF_, f0 + FPS_);

    unsigned long long best = ((unsigned long long)FAR_BITS << 32); // (FAR, fid 0)

    const int* cullp = ((const int*)fdat) + OFF_CULL * NF_;

    for (int base = f0; base < f1; base += 256) {
        int f = base + tid;
        bool pass = false;
        float va=0, vb=0, vc=0, vd=0, vx2=0, vy2=0, vdet=1, vz0=1, vz1=1, vz2=1;
        if (f < f1 && cullp[f] == 0) {
            // tile-vs-bbox overlap (bbox pre-expanded by 1e-4 margin)
            pass = (fdat[OFF_XMIN*NF_+f] <= tpx1) && (fdat[OFF_XMAX*NF_+f] >= tpx0) &&
                   (fdat[OFF_YMIN*NF_+f] <= tpy1) && (fdat[OFF_YMAX*NF_+f] >= tpy0);
            if (pass) {
                va  = fdat[OFF_A*NF_+f];  vb  = fdat[OFF_B*NF_+f];
                vc  = fdat[OFF_C*NF_+f];  vd  = fdat[OFF_D*NF_+f];
                vx2 = fdat[OFF_X2*NF_+f]; vy2 = fdat[OFF_Y2*NF_+f];
                vdet= fdat[OFF_DET*NF_+f];
                vz0 = fdat[OFF_Z0*NF_+f]; vz1 = fdat[OFF_Z1*NF_+f]; vz2 = fdat[OFF_Z2*NF_+f];
            }
        }
        // order-preserving compaction into LDS (keeps ascending fid for tie-break)
        unsigned long long bal = __ballot((int)pass);
        int lane = tid & 63, wv = tid >> 6;
        int woff = __popcll(bal & ((1ull << lane) - 1ull));
        if (lane == 0) wcnt[wv] = (int)__popcll(bal);
        __syncthreads();
        int wbase = 0;
        #pragma unroll
        for (int w = 0; w < 4; ++w) if (w < wv) wbase += wcnt[w];
        int total = wcnt[0] + wcnt[1] + wcnt[2] + wcnt[3];
        if (pass) {
            int p = wbase + woff;
            la[p]=va; lb[p]=vb; lc[p]=vc; ld[p]=vd;
            lx2[p]=vx2; ly2[p]=vy2; ldet[p]=vdet;
            lz0[p]=vz0; lz1[p]=vz1; lz2[p]=vz2;
            lfid[p]=f;
        }
        __syncthreads();

        for (int k = 0; k < total; ++k) {
            float a = la[k], b = lb[k], c = lc[k], d = ld[k];
            float x2 = lx2[k], y2 = ly2[k], dets = ldet[k];
            float dx = px - x2, dy = py - y2;
            float n0 = a * dx + b * dy;
            float n1 = c * dx + d * dy;
            unsigned sd = __float_as_uint(dets) >> 31;
            // w>=0  <=>  num==0 || sign(num)==sign(det)   (exact for IEEE division)
            bool s0 = (n0 == 0.0f) || ((__float_as_uint(n0) >> 31) == sd);
            bool s1 = (n1 == 0.0f) || ((__float_as_uint(n1) >> 31) == sd);
            if (s0 && s1) {
                float w0 = n0 / dets;
                float w1 = n1 / dets;
                float w2 = 1.0f - w0 - w1;
                if (w2 >= 0.0f) {
                    float invz = w0 / lz0[k] + w1 / lz1[k] + w2 / lz2[k];
                    if (invz > INV_FAR_F) {
                        float clz = fminf(fmaxf(invz, INV_FAR_F), INV_NEAR_F);
                        float dep = 1.0f / clz;
                        unsigned long long cand =
                            ((unsigned long long)__float_as_uint(dep) << 32) |
                            (unsigned)lfid[k];
                        if (cand < best) best = cand;   // lexicographic (depth, fid)
                    }
                }
            }
        }
        __syncthreads();  // protect LDS before next chunk
    }

    atomicMin(&pd64[ii * R_ + jj], best);
}

__global__ __launch_bounds__(256) void kfin(const unsigned long long* __restrict__ pd64,
                                            const float* __restrict__ fdat,
                                            const float* __restrict__ tex,
                                            float* __restrict__ out)
{
#pragma clang fp contract(off)
    int p = blockIdx.x * 256 + threadIdx.x;
    if (p >= NPIX_) return;
    int ii = p >> 7, jj = p & 127;

    unsigned long long v = pd64[p];
    float dep = __uint_as_float((unsigned)(v >> 32));
    int f = (int)(unsigned)(v & 0xffffffffu);

    float r = 0.0f, g = 0.0f, bl = 0.0f, s = 0.0f;
    if (dep < HIT_THR_F) {
        s = 1.0f;
        float px = pix_coord(jj);
        float py = -pix_coord(ii);
        float dx = px - fdat[OFF_X2*NF_+f];
        float dy = py - fdat[OFF_Y2*NF_+f];
        float dets = fdat[OFF_DET*NF_+f];
        float w0 = (fdat[OFF_A*NF_+f] * dx + fdat[OFF_B*NF_+f] * dy) / dets;
        float w1 = (fdat[OFF_C*NF_+f] * dx + fdat[OFF_D*NF_+f] * dy) / dets;
        float w2 = 1.0f - w0 - w1;
        float wt0 = (w0 / fdat[OFF_Z0*NF_+f]) * dep;
        float wt1 = (w1 / fdat[OFF_Z1*NF_+f]) * dep;
        float wt2 = (w2 / fdat[OFF_Z2*NF_+f]) * dep;
        int t0 = (int)fminf(fmaxf(floorf(wt0 * 3.0f), 0.0f), 2.0f);
        int t1 = (int)fminf(fmaxf(floorf(wt1 * 3.0f), 0.0f), 2.0f);
        int t2 = (int)fminf(fmaxf(floorf(wt2 * 3.0f), 0.0f), 2.0f);
        int lin = f * 27 + t0 * 9 + t1 * 3 + t2;
        r  = tex[lin * 3 + 0];
        g  = tex[lin * 3 + 1];
        bl = tex[lin * 3 + 2];
    }
    // imgs (1,3,128,128) then sil (1,128,128)
    out[0 * NPIX_ + p] = r;
    out[1 * NPIX_ + p] = g;
    out[2 * NPIX_ + p] = bl;
    out[3 * NPIX_ + p] = s;
}

extern "C" void kernel_launch(void* const* d_in, const int* in_sizes, int n_in,
                              void* d_out, int out_size, void* d_ws, size_t ws_size,
                              hipStream_t stream) {
    const float* verts = (const float*)d_in[0];   // (1, 6890, 3) f32
    const float* tex   = (const float*)d_in[1];   // (1, 13776, 3,3,3,3) f32
    const int*   faces = (const int*)d_in[2];     // (13776, 3) i32
    float* out = (float*)d_out;                   // 49152 imgs + 16384 sil

    char* ws = (char*)d_ws;
    unsigned long long* pd64 = (unsigned long long*)ws;          // 16384 * 8 B
    float* fdat = (float*)(ws + (size_t)NPIX_ * 8);              // 15 * NF_ * 4 B

    kpre <<<(NF_ + 255) / 256, 256, 0, stream>>>(verts, faces, fdat);
    kinit<<<NPIX_ / 256, 256, 0, stream>>>(pd64);
    dim3 g(64, NSLICE_);
    kscan<<<g, 256, 0, stream>>>(fdat, pd64);
    kfin <<<NPIX_ / 256, 256, 0, stream>>>(pd64, fdat, tex, out);
}

// Round 2
// 236.756 us; speedup vs baseline: 1.3627x; 1.3627x over previous
//
#include <hip/hip_runtime.h>
#include <math.h>
#include <stdint.h>

#define NF_     13776
#define R_      128
#define NPIX_   (R_ * R_)
#define CH_     256
#define MAXCH_  ((NF_ + CH_ - 1) / CH_)          // 54
#define NSLICE_ 32
#define FPS_    ((NF_ + NSLICE_ - 1) / NSLICE_)

typedef unsigned long long u64;
typedef unsigned int u32;

// exact f32 constants matching the JAX reference
#define EYEZ_F     (-2.7320508075688772935f)     // -(1/tan(30deg) + 1)
#define INV_FAR_F  (0.04f)
#define INV_NEAR_F (10.0f)
#define FAR_BITS   0x41C80000u                   // bits of 25.0f
#define HIT_THR_F  ((float)(25.0 * (1.0 - 1e-06)))
#define SENTINEL_  (((u64)FAR_BITS << 32))       // depth=FAR, fid=0

static __device__ __forceinline__ float pix_coord(int j) {
    // (2*j + 1 - 128)/128 : exact in f32
    return (2.0f * (float)j + 1.0f - 128.0f) / 128.0f;
}

// ---------------- per-face preprocess (AoS float4 records) ----------------
__global__ __launch_bounds__(256) void kpre(const float* __restrict__ verts,
                                            const int* __restrict__ faces,
                                            float4* __restrict__ fq0,
                                            float4* __restrict__ fq1,
                                            float4* __restrict__ fq2,
                                            float4* __restrict__ bbx,
                                            int* __restrict__ cull)
{
#pragma clang fp contract(off)
    int f = blockIdx.x * 256 + threadIdx.x;
    if (f >= NF_) return;
    int i0 = faces[3*f+0], i1 = faces[3*f+1], i2 = faces[3*f+2];
    float x0 = verts[3*i0+0], y0 = verts[3*i0+1], z0 = verts[3*i0+2] - EYEZ_F;
    float x1 = verts[3*i1+0], y1 = verts[3*i1+1], z1 = verts[3*i1+2] - EYEZ_F;
    float x2 = verts[3*i2+0], y2 = verts[3*i2+1], z2 = verts[3*i2+2] - EYEZ_F;

    float a = y1 - y2;
    float b = x2 - x1;
    float c = y2 - y0;
    float d = x0 - x2;
    float e = y0 - y2;
    float det = a * d + b * e;                   // no FMA (contract off)
    bool det_ok = fabsf(det) > 1e-10f;
    float dets = det_ok ? det : 1e-10f;
    bool zpos = (z0 > 0.1f) && (z1 > 0.1f) && (z2 > 0.1f);

    // conservative prune bound: valid candidate depth >= zmin*(1 - few ulp)
    float zmin_eff = fminf(z0, fminf(z1, z2)) * 0.99999f;

    fq0[f] = make_float4(a, b, c, d);
    fq1[f] = make_float4(x2, y2, dets, zmin_eff);
    fq2[f] = make_float4(z0, z1, z2, __uint_as_float((u32)f));
    bbx[f] = make_float4(fminf(x0, fminf(x1, x2)) - 1e-4f,
                         fmaxf(x0, fmaxf(x1, x2)) + 1e-4f,
                         fminf(y0, fminf(y1, y2)) - 1e-4f,
                         fmaxf(y0, fmaxf(y1, y2)) + 1e-4f);
    cull[f] = (det_ok && zpos) ? 0 : 1;
}

// ---------------- init depth buffer + bin counters ----------------
__global__ __launch_bounds__(256) void kinit(u64* __restrict__ pd64, int* __restrict__ fill)
{
    int p = blockIdx.x * 256 + threadIdx.x;
    if (p < NPIX_) pd64[p] = SENTINEL_;
    if (p < 64)    fill[p] = 0;
}

// ---------------- bin faces into per-tile lists ----------------
__global__ __launch_bounds__(256) void kbin(const float4* __restrict__ bbx,
                                            const int* __restrict__ cull,
                                            int* __restrict__ fill,
                                            int* __restrict__ list)
{
#pragma clang fp contract(off)
    int f = blockIdx.x * 256 + threadIdx.x;
    if (f >= NF_ || cull[f]) return;
    float4 bb = bbx[f];   // xmin,xmax,ymin,ymax (pre-expanded)
    int xm = 0, ym = 0;
    for (int t = 0; t < 8; ++t) {
        float tx0 = pix_coord(t * 16), tx1 = pix_coord(t * 16 + 15);
        if (bb.x <= tx1 && bb.y >= tx0) xm |= 1 << t;
        float ty1 = -pix_coord(t * 16), ty0 = -pix_coord(t * 16 + 15);
        if (bb.z <= ty1 && bb.w >= ty0) ym |= 1 << t;
    }
    for (int tr = 0; tr < 8; ++tr) if (ym & (1 << tr))
        for (int tc = 0; tc < 8; ++tc) if (xm & (1 << tc)) {
            int t = tr * 8 + tc;
            int slot = atomicAdd(&fill[t], 1);
            list[t * NF_ + slot] = f;
        }
}

// ---------------- balanced scan: block = (tile, chunk of 256 candidates) ----------------
__global__ __launch_bounds__(256) void kscan2(const float4* __restrict__ fq0,
                                              const float4* __restrict__ fq1,
                                              const float4* __restrict__ fq2,
                                              const int* __restrict__ fill,
                                              const int* __restrict__ list,
                                              u64* __restrict__ pd64)
{
#pragma clang fp contract(off)
    __shared__ float4 cd[CH_][3];
    const int t = blockIdx.x, c = blockIdx.y;
    const int len = fill[t];
    const int base = c * CH_;
    if (base >= len) return;
    const int K = min(CH_, len - base);
    const int tid = threadIdx.x;
    if (tid < K) {
        int f = list[t * NF_ + base + tid];
        cd[tid][0] = fq0[f];
        cd[tid][1] = fq1[f];
        cd[tid][2] = fq2[f];
    }
    __syncthreads();

    const int ii = (t >> 3) * 16 + (tid >> 4);
    const int jj = (t & 7) * 16 + (tid & 15);
    const int p  = ii * R_ + jj;
    const float px = pix_coord(jj);
    const float py = -pix_coord(ii);

    // monotone 4B read of current depth word: stale => larger => safe bound
    u32 seed = ((const volatile u32*)pd64)[2 * p + 1];
    u64 best = ((u64)seed << 32) | 0xFFFFFFFFull;
    float bestd = __uint_as_float(seed);

    for (int k = 0; k < K; ++k) {
        float4 q1 = cd[k][1];                 // x2,y2,det,zmin_eff
        if (q1.w > bestd) continue;           // strict: preserves exact ties
        float4 q0 = cd[k][0];                 // a,b,c,d
        float dx = px - q1.x, dy = py - q1.y;
        float n0 = q0.x * dx + q0.y * dy;
        float n1 = q0.z * dx + q0.w * dy;
        u32 sd = __float_as_uint(q1.z) >> 31;
        bool s0 = (n0 == 0.0f) || ((__float_as_uint(n0) >> 31) == sd);
        bool s1 = (n1 == 0.0f) || ((__float_as_uint(n1) >> 31) == sd);
        if (!(s0 && s1)) continue;
        float w0 = n0 / q1.z;
        float w1 = n1 / q1.z;
        float w2 = 1.0f - w0 - w1;
        if (!(w2 >= 0.0f)) continue;
        float4 q2 = cd[k][2];                 // z0,z1,z2,fid
        float invz = w0 / q2.x + w1 / q2.y + w2 / q2.z;
        if (invz > INV_FAR_F) {
            float clz = fminf(fmaxf(invz, INV_FAR_F), INV_NEAR_F);
            float dep = 1.0f / clz;
            u64 cand = ((u64)__float_as_uint(dep) << 32) | (u64)__float_as_uint(q2.w);
            if (cand < best) { best = cand; bestd = __uint_as_float((u32)(best >> 32)); }
        }
    }
    if ((u32)best != 0xFFFFFFFFu) atomicMin(&pd64[p], best);
}

// ---------------- fallback: slice scan without lists (if ws too small) ----------------
__global__ __launch_bounds__(256) void kscanS(const float4* __restrict__ fq0,
                                              const float4* __restrict__ fq1,
                                              const float4* __restrict__ fq2,
                                              const float4* __restrict__ bbx,
                                              const int* __restrict__ cull,
                                              u64* __restrict__ pd64)
{
#pragma clang fp contract(off)
    const int t = blockIdx.x, s = blockIdx.y;
    const int tid = threadIdx.x;
    const int ii = (t >> 3) * 16 + (tid >> 4);
    const int jj = (t & 7) * 16 + (tid & 15);
    const int p  = ii * R_ + jj;
    const float px = pix_coord(jj);
    const float py = -pix_coord(ii);
    const float tpx0 = pix_coord((t & 7) * 16), tpx1 = pix_coord((t & 7) * 16 + 15);
    const float tpy1 = -pix_coord((t >> 3) * 16), tpy0 = -pix_coord((t >> 3) * 16 + 15);
    const int f0 = s * FPS_, f1 = min(NF_, f0 + FPS_);

    u32 seed = ((const volatile u32*)pd64)[2 * p + 1];
    u64 best = ((u64)seed << 32) | 0xFFFFFFFFull;
    float bestd = __uint_as_float(seed);

    for (int f = f0; f < f1; ++f) {
        if (cull[f]) continue;
        float4 bb = bbx[f];
        if (!(bb.x <= tpx1 && bb.y >= tpx0 && bb.z <= tpy1 && bb.w >= tpy0)) continue;
        float4 q1 = fq1[f];
        if (q1.w > bestd) continue;
        float4 q0 = fq0[f];
        float dx = px - q1.x, dy = py - q1.y;
        float n0 = q0.x * dx + q0.y * dy;
        float n1 = q0.z * dx + q0.w * dy;
        u32 sd = __float_as_uint(q1.z) >> 31;
        bool s0 = (n0 == 0.0f) || ((__float_as_uint(n0) >> 31) == sd);
        bool s1 = (n1 == 0.0f) || ((__float_as_uint(n1) >> 31) == sd);
        if (!(s0 && s1)) continue;
        float w0 = n0 / q1.z;
        float w1 = n1 / q1.z;
        float w2 = 1.0f - w0 - w1;
        if (!(w2 >= 0.0f)) continue;
        float4 q2 = fq2[f];
        float invz = w0 / q2.x + w1 / q2.y + w2 / q2.z;
        if (invz > INV_FAR_F) {
            float clz = fminf(fmaxf(invz, INV_FAR_F), INV_NEAR_F);
            float dep = 1.0f / clz;
            u64 cand = ((u64)__float_as_uint(dep) << 32) | (u64)__float_as_uint(q2.w);
            if (cand < best) { best = cand; bestd = __uint_as_float((u32)(best >> 32)); }
        }
    }
    if ((u32)best != 0xFFFFFFFFu) atomicMin(&pd64[p], best);
}

// ---------------- finalize: texel gather + outputs ----------------
__global__ __launch_bounds__(256) void kfin(const u64* __restrict__ pd64,
                                            const float4* __restrict__ fq0,
                                            const float4* __restrict__ fq1,
                                            const float4* __restrict__ fq2,
                                            const float* __restrict__ tex,
                                            float* __restrict__ out)
{
#pragma clang fp contract(off)
    int p = blockIdx.x * 256 + threadIdx.x;
    if (p >= NPIX_) return;
    int ii = p >> 7, jj = p & 127;

    u64 v = pd64[p];
    float dep = __uint_as_float((u32)(v >> 32));
    int f = (int)(u32)v;

    float r = 0.0f, g = 0.0f, bl = 0.0f, s = 0.0f;
    if (dep < HIT_THR_F) {
        s = 1.0f;
        float4 q0 = fq0[f], q1 = fq1[f], q2 = fq2[f];
        float px = pix_coord(jj);
        float py = -pix_coord(ii);
        float dx = px - q1.x, dy = py - q1.y;
        float w0 = (q0.x * dx + q0.y * dy) / q1.z;
        float w1 = (q0.z * dx + q0.w * dy) / q1.z;
        float w2 = 1.0f - w0 - w1;
        float wt0 = (w0 / q2.x) * dep;
        float wt1 = (w1 / q2.y) * dep;
        float wt2 = (w2 / q2.z) * dep;
        int t0 = (int)fminf(fmaxf(floorf(wt0 * 3.0f), 0.0f), 2.0f);
        int t1 = (int)fminf(fmaxf(floorf(wt1 * 3.0f), 0.0f), 2.0f);
        int t2 = (int)fminf(fmaxf(floorf(wt2 * 3.0f), 0.0f), 2.0f);
        int lin = f * 27 + t0 * 9 + t1 * 3 + t2;
        r  = tex[lin * 3 + 0];
        g  = tex[lin * 3 + 1];
        bl = tex[lin * 3 + 2];
    }
    out[0 * NPIX_ + p] = r;
    out[1 * NPIX_ + p] = g;
    out[2 * NPIX_ + p] = bl;
    out[3 * NPIX_ + p] = s;
}

extern "C" void kernel_launch(void* const* d_in, const int* in_sizes, int n_in,
                              void* d_out, int out_size, void* d_ws, size_t ws_size,
                              hipStream_t stream) {
    const float* verts = (const float*)d_in[0];
    const float* tex   = (const float*)d_in[1];
    const int*   faces = (const int*)d_in[2];
    float* out = (float*)d_out;

    char* ws = (char*)d_ws;
    size_t off = 0;
    u64*    pd64 = (u64*)   (ws + off); off += (size_t)NPIX_ * 8;
    float4* fq0  = (float4*)(ws + off); off += (size_t)NF_ * 16;
    float4* fq1  = (float4*)(ws + off); off += (size_t)NF_ * 16;
    float4* fq2  = (float4*)(ws + off); off += (size_t)NF_ * 16;
    float4* bbx  = (float4*)(ws + off); off += (size_t)NF_ * 16;
    int*    cull = (int*)   (ws + off); off += (size_t)NF_ * 4;
    int*    fill = (int*)   (ws + off); off += 64 * 4;
    off = (off + 15) & ~(size_t)15;
    int*    list = (int*)   (ws + off);
    size_t need = off + (size_t)64 * NF_ * 4;

    kpre <<<(NF_ + 255) / 256, 256, 0, stream>>>(verts, faces, fq0, fq1, fq2, bbx, cull);
    kinit<<<NPIX_ / 256, 256, 0, stream>>>(pd64, fill);
    if (ws_size >= need) {
        kbin<<<(NF_ + 255) / 256, 256, 0, stream>>>(bbx, cull, fill, list);
        dim3 g(64, MAXCH_);
        kscan2<<<g, 256, 0, stream>>>(fq0, fq1, fq2, fill, list, pd64);
    } else {
        dim3 g(64, NSLICE_);
        kscanS<<<g, 256, 0, stream>>>(fq0, fq1, fq2, bbx, cull, pd64);
    }
    kfin<<<NPIX_ / 256, 256, 0, stream>>>(pd64, fq0, fq1, fq2, tex, out);
}